// Round 11
// baseline (376.248 us; speedup 1.0000x reference)
//
#include <hip/hip_runtime.h>
#include <hip/hip_bf16.h>

// Problem constants
#define NB    8
#define SQN   2048
#define SKN   4096
#define DDIM  512
#define DVDIM 256
#define NROWS (NB*SQN)      // 16384
#define NS    2             // SK splits
#define NJ    ((SKN/64)/NS) // 32 j-iterations per split (64 keys each)

typedef __attribute__((ext_vector_type(8)))  short bf16x8;   // 8 bf16 = 4 VGPRs (MFMA A/B frag)
typedef __attribute__((ext_vector_type(4)))  short bf16x4;
typedef __attribute__((ext_vector_type(4)))  float f32x4;    // 16x16 MFMA C/D frag
typedef __attribute__((ext_vector_type(16))) float f32x16;   // 32x32 MFMA C/D frag

// fp32 -> bf16 round-to-nearest-even, bit pattern as short
__device__ __forceinline__ short f2bf(float f) {
    unsigned u = __float_as_uint(f);
    return (short)((u + 0x7FFFu + ((u >> 16) & 1u)) >> 16);
}

// ---------------------------------------------------------------------------
// Fused projection GEMMs, one launch. grid = (64, 8, 2).  (unchanged from R8)
// Epilogues write K/V PRE-PACKED in fragment-lane order (16B units;
// lane = hi*32 + l31):
//  K: frag(tau,kh) at byte J*65536 + tau*2048 + kh*1024   (tau = k-step 0..31)
//  V: frag(n,g)    at byte J*32768 + (n>>2)*16384 + (n&3)*4096 + g*1024
// ---------------------------------------------------------------------------
__global__ __launch_bounds__(256, 2) void proj_gemms(
    const float* __restrict__ Y, const float* __restrict__ Z,
    const float* __restrict__ Wk, const float* __restrict__ Wv,
    unsigned short* __restrict__ keyb, unsigned short* __restrict__ vtb)
{
    __shared__ short sA[64*128];   // 16 KB
    __shared__ short sB[64*128];   // 16 KB
    const float *A, *Bm;
    unsigned short* C;
    int m0, n0;
    const bool kpath = (blockIdx.z == 0);
    if (kpath) {
        A = Y; Bm = Wk; C = keyb;
        m0 = blockIdx.x * 64; n0 = blockIdx.y * 64;
    } else {
        int lin = blockIdx.x * 8 + blockIdx.y;
        if (lin >= 256) return;                 // value GEMM needs 256 tiles
        A = Wv; Bm = Z; C = vtb;
        m0 = (lin >> 6) * 64; n0 = (lin & 63) * 64;
    }
    const int tid  = threadIdx.x;
    const int wave = tid >> 6;
    const int lane = tid & 63;
    const int quad = lane >> 4;
    const int l15  = lane & 15;

    f32x4 acc[4];
    #pragma unroll
    for (int n = 0; n < 4; ++n) { acc[n][0]=0.f; acc[n][1]=0.f; acc[n][2]=0.f; acc[n][3]=0.f; }

    float4 ra[8], rb[8];
    #pragma unroll
    for (int it = 0; it < 8; ++it) {            // prefetch kc=0
        int f = it*1024 + tid*4, row = f >> 7, col = f & 127;
        ra[it] = *(const float4*)(A  + (size_t)(m0+row)*DDIM + col);
        rb[it] = *(const float4*)(Bm + (size_t)(n0+row)*DDIM + col);
    }

    for (int kc = 0; kc < DDIM; kc += 128) {
        __syncthreads();                        // LDS free (prev MFMA done)
        #pragma unroll
        for (int it = 0; it < 8; ++it) {
            int f = it*1024 + tid*4;
            bf16x4 a4; a4[0]=f2bf(ra[it].x); a4[1]=f2bf(ra[it].y); a4[2]=f2bf(ra[it].z); a4[3]=f2bf(ra[it].w);
            *(bf16x4*)(sA + f) = a4;
            bf16x4 b4; b4[0]=f2bf(rb[it].x); b4[1]=f2bf(rb[it].y); b4[2]=f2bf(rb[it].z); b4[3]=f2bf(rb[it].w);
            *(bf16x4*)(sB + f) = b4;
        }
        __syncthreads();                        // staged visible
        if (kc + 128 < DDIM) {                  // prefetch kc+1 (in flight under MFMA)
            #pragma unroll
            for (int it = 0; it < 8; ++it) {
                int f = it*1024 + tid*4, row = f >> 7, col = f & 127;
                ra[it] = *(const float4*)(A  + (size_t)(m0+row)*DDIM + kc + 128 + col);
                rb[it] = *(const float4*)(Bm + (size_t)(n0+row)*DDIM + kc + 128 + col);
            }
        }
        #pragma unroll
        for (int t = 0; t < 4; ++t) {
            bf16x8 af = *(const bf16x8*)(sA + (wave*16 + l15)*128 + t*32 + quad*8);
            #pragma unroll
            for (int n = 0; n < 4; ++n) {
                bf16x8 bfr = *(const bf16x8*)(sB + (n*16 + l15)*128 + t*32 + quad*8);
                acc[n] = __builtin_amdgcn_mfma_f32_16x16x32_bf16(af, bfr, acc[n], 0, 0, 0);
            }
        }
    }
    // packed epilogue
    #pragma unroll
    for (int n = 0; n < 4; ++n)
        #pragma unroll
        for (int r = 0; r < 4; ++r) {
            int m  = m0 + wave*16 + quad*4 + r;
            int nn = n0 + n*16 + l15;
            unsigned short v = (unsigned short)f2bf(acc[n][r]);
            size_t off;
            if (kpath) {        // s=m (key row), d=nn
                int J = m >> 6, kh = (m >> 5) & 1, ls = m & 31;
                int c = nn >> 7, tp = (nn >> 4) & 7, hd = (nn >> 3) & 1, d7 = nn & 7;
                off = (size_t)(((J*4 + c)*8 + tp)*2 + kh)*512 + (hd*32 + ls)*8 + d7;
            } else {            // dv=m, key=nn
                int J = nn >> 6, g = (nn >> 4) & 3, hk = (nn >> 3) & 1, k7 = nn & 7;
                int wv = m >> 7, n2 = (m >> 5) & 3, lv = m & 31;
                off = (size_t)((J*8 + wv*4 + n2)*4 + g)*512 + (hk*32 + lv)*8 + k7;
            }
            C[off] = v;
        }
}

// ---------------------------------------------------------------------------
// Fused attention, R11: BARRIER-FREE INDEPENDENT WAVES.
// R8-R10 diagnosis: the wk-pair key split forces 2 exchange barriers/j that
// phase-lock the waves -> MFMA phases collide, VALU phases collide, window
// = sum of pipes (11-12k cyc/j) not max. R10's intra-wave pipeline spilled
// (256-VGPR arch cap; FETCH/WRITE +15MB scratch).
// Fix: each wave owns 32 Q-rows x FULL 64-key tile x FULL 256 dv:
//  - two QK accumulators sc0/sc1 (key-halves), 64 QK MFMAs/j
//  - softmax 100% wave-local (32-reg max + one shfl_xor(32)); pf[4] built
//    in-register (proven cvt_pk+permlane); NO sPex, NO sSt, NO barriers.
//  - PV: o[8] over all dv, 32 MFMAs/j.
// Register audit FIRST (R10 lesson): arch = kf64+vf64+pf16+temps ~170 <=256;
// acc-class = o128+sc32 = 160 <=256. No spill possible.
// K ring: 4 banks x 4-frag stages (16 stages/j, 16%4==0 -> static indices),
// prefetch distance 3 (~384 cyc > L2 latency). V: 2 banks, R8's reload
// pattern. Next-j stages 0,1,2 fill st==15 and PV g0/g1 slots.
// Q wave-private LDS (32KB/wave; same-wave ds_write->ds_read, no barrier).
// grid = 512 (2 blocks/CU, 4 indep waves/CU), block = 128.
// T13 defer-max log2 softmax; XCD-split swizzle keeps K/V L2-resident.
// ---------------------------------------------------------------------------
__global__ __launch_bounds__(128, 1) void attn_fused(
    const float* __restrict__ X,            // [16384][512] fp32
    const unsigned short* __restrict__ Kb,  // key bf16, PACKED (4 MB)
    const unsigned short* __restrict__ Vt,  // V^T bf16, PACKED (2 MB)
    float* __restrict__ Opart,              // [NS][16384][256]
    float* __restrict__ Mpart,              // [NS][16384] (log2 domain)
    float* __restrict__ Lpart)              // [NS][16384]
{
    // wave-private Q: [wave][t2=32][lane]x16B
    __shared__ __align__(16) char smem[65536];

    const int tid  = threadIdx.x;
    const int wave = tid >> 6;      // 0..1
    const int lane = tid & 63;
    const int l31  = lane & 31;
    const int hi   = lane >> 5;

    // XCD-split swizzle: bid&7 = XCD; XCD 0-3 -> split 0, 4-7 -> split 1.
    const int bid   = blockIdx.x;          // 0..511
    const int xcd   = bid & 7;
    const int slot  = bid >> 3;            // 0..63
    const int split = xcd >> 2;
    const int q0w   = ((xcd & 3)*64 + slot)*64 + wave*32;  // this wave's rows
    // 1/sqrt(512) * log2(e): softmax runs in log2 domain (exp2)
    const float scale = 0.04419417382415922f * 1.4426950408889634f;

    // ---- prologue: stage this wave's 32 Q frag-tiles (wave-private LDS;
    //      same-wave ds_write->ds_read needs no barrier) ----
    char* sQw = smem + wave*32768;
    {
        const float* xrow = X + (size_t)(q0w + l31)*DDIM + hi*8;
        #pragma unroll
        for (int t2 = 0; t2 < 32; ++t2) {
            float4 a = *(const float4*)(xrow + t2*16);
            float4 b = *(const float4*)(xrow + t2*16 + 4);
            bf16x8 q;
            q[0]=f2bf(a.x*scale); q[1]=f2bf(a.y*scale); q[2]=f2bf(a.z*scale); q[3]=f2bf(a.w*scale);
            q[4]=f2bf(b.x*scale); q[5]=f2bf(b.y*scale); q[6]=f2bf(b.z*scale); q[7]=f2bf(b.w*scale);
            *(bf16x8*)(sQw + t2*1024 + lane*16) = q;
        }
    }

    // O acc: D[row=q][col=dv], dv = n*32 + l31, n=0..7.  (acc-class regs)
    f32x16 o[8];
    #pragma unroll
    for (int n = 0; n < 8; ++n)
        #pragma unroll
        for (int r = 0; r < 16; ++r) o[n][r] = 0.f;
    float m_r = -1e30f, l_r = 0.f;       // per-lane (q = l31), wave-local

    // packed base pointers (lane folded in); kp/vp advance per j
    const char* kp = (const char*)Kb + (size_t)split*NJ*65536 + lane*16;
    const char* vp = (const char*)Vt + (size_t)split*NJ*32768 + lane*16;

    bf16x8 kf[4][4];                    // 4 banks x {tt*2+kh} (64 VGPR)
    bf16x8 vf[2][8];                    // 2 banks x {n}       (64 VGPR)

    // load K stage (2 k-steps x 2 kh = 4 frags) at byte offset boff_
    #define LD_KS(bank_, boff_)                                               \
        do { _Pragma("unroll")                                                \
             for (int tt_ = 0; tt_ < 2; ++tt_)                                \
                 _Pragma("unroll")                                            \
                 for (int kh_ = 0; kh_ < 2; ++kh_)                            \
                     kf[bank_][tt_*2 + kh_] = *(const bf16x8*)(kp + (boff_)   \
                         + tt_*2048 + kh_*1024);                              \
        } while (0)

    // load V window g_ (8 n-frags) of current j
    #define LD_VG(bank_, g_)                                                  \
        do { _Pragma("unroll")                                                \
             for (int n_ = 0; n_ < 8; ++n_)                                   \
                 vf[bank_][n_] = *(const bf16x8*)(vp + (n_>>2)*16384          \
                     + (n_&3)*4096 + (g_)*1024);                              \
        } while (0)

    const char* qb = sQw + lane*16;

    // prologue K loads: stages 0,1,2 of j=0
    LD_KS(0, 0); LD_KS(1, 4096); LD_KS(2, 8192);

    for (int j = 0; j < NJ; ++j) {
        const bool hasN = (j + 1 < NJ);
        f32x16 sc0, sc1;                // P^T acc per key-half: D[key][q]
        #pragma unroll
        for (int r = 0; r < 16; ++r) { sc0[r] = 0.f; sc1[r] = 0.f; }

        // ---- QK: 16 stages x 4 MFMA; ring-4, prefetch distance 3;
        //      V g0/g1 at st 13/14; next-j stage0 at st 15 ----
        #pragma unroll
        for (int st = 0; st < 16; ++st) {
            if (st < 13)       LD_KS((st + 3) & 3, (st + 3)*4096);
            else if (st == 13) LD_VG(0, 0);
            else if (st == 14) LD_VG(1, 1);
            else if (hasN)     LD_KS(0, 65536);     // next-j stage 0 -> bank0
            __builtin_amdgcn_s_setprio(1);
            {
                bf16x8 qa = *(const bf16x8*)(qb + (st*2 + 0)*1024);
                bf16x8 qc = *(const bf16x8*)(qb + (st*2 + 1)*1024);
                sc0 = __builtin_amdgcn_mfma_f32_32x32x16_bf16(kf[st & 3][0], qa, sc0, 0, 0, 0);
                sc1 = __builtin_amdgcn_mfma_f32_32x32x16_bf16(kf[st & 3][1], qa, sc1, 0, 0, 0);
                sc0 = __builtin_amdgcn_mfma_f32_32x32x16_bf16(kf[st & 3][2], qc, sc0, 0, 0, 0);
                sc1 = __builtin_amdgcn_mfma_f32_32x32x16_bf16(kf[st & 3][3], qc, sc1, 0, 0, 0);
            }
            __builtin_amdgcn_s_setprio(0);
        }

        // ---- softmax (log2 domain), fully wave-local ----
        float tmax;
        {
            float v = fmaxf(fmaxf(fmaxf(sc0[0],sc0[1]),fmaxf(sc0[2],sc0[3])),
                            fmaxf(fmaxf(sc0[4],sc0[5]),fmaxf(sc0[6],sc0[7])));
            v = fmaxf(v, fmaxf(fmaxf(fmaxf(sc0[8],sc0[9]),fmaxf(sc0[10],sc0[11])),
                               fmaxf(fmaxf(sc0[12],sc0[13]),fmaxf(sc0[14],sc0[15]))));
            float w = fmaxf(fmaxf(fmaxf(sc1[0],sc1[1]),fmaxf(sc1[2],sc1[3])),
                            fmaxf(fmaxf(sc1[4],sc1[5]),fmaxf(sc1[6],sc1[7])));
            w = fmaxf(w, fmaxf(fmaxf(fmaxf(sc1[8],sc1[9]),fmaxf(sc1[10],sc1[11])),
                               fmaxf(fmaxf(sc1[12],sc1[13]),fmaxf(sc1[14],sc1[15]))));
            v = fmaxf(v, w);
            v = fmaxf(v, __shfl_xor(v, 32));
            tmax = v;
        }
        const bool  upd   = tmax > m_r + 8.0f;      // T13 defer-max
        const float mn    = upd ? tmax : m_r;
        const float alpha = upd ? exp2f(m_r - mn) : 1.0f;
        float tsum = 0.f;
        #pragma unroll
        for (int r = 0; r < 16; ++r) { float pv = exp2f(sc0[r] - mn); sc0[r] = pv; tsum += pv; }
        #pragma unroll
        for (int r = 0; r < 16; ++r) { float pv = exp2f(sc1[r] - mn); sc1[r] = pv; tsum += pv; }
        tsum += __shfl_xor(tsum, 32);
        l_r = l_r*alpha + tsum;
        m_r = mn;

        // P -> PV A-frags in-register: sc0 -> pf[0,1] (keys 0-31),
        // sc1 -> pf[2,3] (keys 32-63). Proven cvt_pk + permlane machinery.
        bf16x8 pf[4];
        #pragma unroll
        for (int kh = 0; kh < 2; ++kh) {
            #pragma unroll
            for (int ks = 0; ks < 2; ++ks) {
                int wA, wB, wC, wD;
                if (kh == 0) {
                    asm("v_cvt_pk_bf16_f32 %0, %1, %2" : "=v"(wA) : "v"(sc0[8*ks+0]), "v"(sc0[8*ks+1]));
                    asm("v_cvt_pk_bf16_f32 %0, %1, %2" : "=v"(wB) : "v"(sc0[8*ks+2]), "v"(sc0[8*ks+3]));
                    asm("v_cvt_pk_bf16_f32 %0, %1, %2" : "=v"(wC) : "v"(sc0[8*ks+4]), "v"(sc0[8*ks+5]));
                    asm("v_cvt_pk_bf16_f32 %0, %1, %2" : "=v"(wD) : "v"(sc0[8*ks+6]), "v"(sc0[8*ks+7]));
                } else {
                    asm("v_cvt_pk_bf16_f32 %0, %1, %2" : "=v"(wA) : "v"(sc1[8*ks+0]), "v"(sc1[8*ks+1]));
                    asm("v_cvt_pk_bf16_f32 %0, %1, %2" : "=v"(wB) : "v"(sc1[8*ks+2]), "v"(sc1[8*ks+3]));
                    asm("v_cvt_pk_bf16_f32 %0, %1, %2" : "=v"(wC) : "v"(sc1[8*ks+4]), "v"(sc1[8*ks+5]));
                    asm("v_cvt_pk_bf16_f32 %0, %1, %2" : "=v"(wD) : "v"(sc1[8*ks+6]), "v"(sc1[8*ks+7]));
                }
                asm("v_permlane32_swap_b32 %0, %1" : "+v"(wA), "+v"(wC));
                asm("v_permlane32_swap_b32 %0, %1" : "+v"(wB), "+v"(wD));
                union { int w[4]; bf16x8 v; } u;
                u.w[0] = wA; u.w[1] = wB; u.w[2] = wC; u.w[3] = wD;
                pf[kh*2 + ks] = u.v;
            }
        }

        if (__any(upd)) {               // rescale O (alpha indexed by q-row)
            #pragma unroll
            for (int r = 0; r < 16; ++r) {
                int row = (r&3) + 8*(r>>2) + 4*hi;
                float ar = __shfl(alpha, row);
                #pragma unroll
                for (int n = 0; n < 8; ++n) o[n][r] *= ar;
            }
        }

        // ---- PV: o[n] += pf[g] * vf; reload V g2/g3 + next-j K stages 1,2
        //      in the gaps (R8's proven WAR-safe pattern) ----
        __builtin_amdgcn_s_setprio(1);
        #pragma unroll
        for (int n = 0; n < 8; ++n)
            o[n] = __builtin_amdgcn_mfma_f32_32x32x16_bf16(pf[0], vf[0][n], o[n], 0, 0, 0);
        __builtin_amdgcn_s_setprio(0);
        LD_VG(0, 2);                                    // g2 -> bank0
        if (hasN) LD_KS(1, 65536 + 4096);               // next-j stage1 -> bank1
        __builtin_amdgcn_s_setprio(1);
        #pragma unroll
        for (int n = 0; n < 8; ++n)
            o[n] = __builtin_amdgcn_mfma_f32_32x32x16_bf16(pf[1], vf[1][n], o[n], 0, 0, 0);
        __builtin_amdgcn_s_setprio(0);
        LD_VG(1, 3);                                    // g3 -> bank1
        if (hasN) LD_KS(2, 65536 + 8192);               // next-j stage2 -> bank2
        __builtin_amdgcn_s_setprio(1);
        #pragma unroll
        for (int n = 0; n < 8; ++n)
            o[n] = __builtin_amdgcn_mfma_f32_32x32x16_bf16(pf[2], vf[0][n], o[n], 0, 0, 0);
        #pragma unroll
        for (int n = 0; n < 8; ++n)
            o[n] = __builtin_amdgcn_mfma_f32_32x32x16_bf16(pf[3], vf[1][n], o[n], 0, 0, 0);
        __builtin_amdgcn_s_setprio(0);

        kp += 65536;
        vp += 32768;
    }
    #undef LD_KS
    #undef LD_VG

    // ---- epilogue: unnormalized O + (m,l) per row; wave owns its rows ----
    const size_t base = (size_t)split * NROWS;
    if (lane < 32) {
        Mpart[base + q0w + lane] = m_r;     // log2 domain
        Lpart[base + q0w + lane] = l_r;
    }
    #pragma unroll
    for (int r = 0; r < 16; ++r) {
        int row = (r&3) + 8*(r>>2) + 4*hi;
        float* orow = Opart + (base + q0w + row) * (size_t)DVDIM;
        #pragma unroll
        for (int n = 0; n < 8; ++n)
            orow[n*32 + l31] = o[n][r];
    }
}

// ---------------------------------------------------------------------------
// Combine NS split partials: out = sum_s(Os*ws) / sum_s(ls*ws), ws=2^(ms-M)
// (Mpart is log2-domain). grid = NROWS/4, block = 256. Coalesced.
// ---------------------------------------------------------------------------
__global__ void combine_splits(
    const float* __restrict__ Opart, const float* __restrict__ Mpart,
    const float* __restrict__ Lpart, float* __restrict__ out)
{
    const int row = blockIdx.x * 4 + (threadIdx.x >> 6);
    const int dv4 = (threadIdx.x & 63) * 4;
    float M = -1e30f;
    #pragma unroll
    for (int s = 0; s < NS; ++s) M = fmaxf(M, Mpart[(size_t)s*NROWS + row]);
    float denom = 0.f;
    float4 acc = make_float4(0.f, 0.f, 0.f, 0.f);
    #pragma unroll
    for (int s = 0; s < NS; ++s) {
        float w = exp2f(Mpart[(size_t)s*NROWS + row] - M);
        denom += Lpart[(size_t)s*NROWS + row] * w;
        float4 ov = *(const float4*)(Opart + ((size_t)s*NROWS + row)*DVDIM + dv4);
        acc.x += ov.x*w; acc.y += ov.y*w; acc.z += ov.z*w; acc.w += ov.w*w;
    }
    float inv = 1.0f / denom;
    *(float4*)(out + (size_t)row*DVDIM + dv4)
        = make_float4(acc.x*inv, acc.y*inv, acc.z*inv, acc.w*inv);
}

extern "C" void kernel_launch(void* const* d_in, const int* in_sizes, int n_in,
                              void* d_out, int out_size, void* d_ws, size_t ws_size,
                              hipStream_t stream) {
    const float* X  = (const float*)d_in[0];   // [8,2048,512]
    const float* Y  = (const float*)d_in[1];   // [4096,512]
    const float* Z  = (const float*)d_in[2];   // [4096,512]
    const float* Wk = (const float*)d_in[3];   // [512,512]
    const float* Wv = (const float*)d_in[4];   // [256,512]
    float* out = (float*)d_out;

    // workspace layout (~38.3 MB)
    char* ws = (char*)d_ws;
    unsigned short* keyb = (unsigned short*)ws;                    // 4 MB, PACKED
    unsigned short* vtb  = (unsigned short*)(ws + (4u<<20));       // 2 MB, PACKED
    float* Opart = (float*)(ws + (6u<<20));                        // NS x 16 MB
    float* Mpart = (float*)(ws + (6u<<20) + (size_t)NS*NROWS*DVDIM*4);
    float* Lpart = Mpart + (size_t)NS*NROWS;

    // both projections, one launch (epilogues emit packed layouts)
    proj_gemms<<<dim3(64, 8, 2), dim3(256), 0, stream>>>(Y, Z, Wk, Wv, keyb, vtb);
    // fused attention: 512 blocks (2/CU), barrier-free independent waves
    attn_fused<<<dim3(512), dim3(128), 0, stream>>>(
        X, keyb, vtb, Opart, Mpart, Lpart);
    // merge splits
    combine_splits<<<dim3(NROWS/4), dim3(256), 0, stream>>>(Opart, Mpart, Lpart, out);
}

// Round 12
// 259.080 us; speedup vs baseline: 1.4522x; 1.4522x over previous
//
#include <hip/hip_runtime.h>
#include <hip/hip_bf16.h>

// Problem constants
#define NB    8
#define SQN   2048
#define SKN   4096
#define DDIM  512
#define DVDIM 256
#define NROWS (NB*SQN)      // 16384
#define NS    2             // SK splits
#define NJ    ((SKN/64)/NS) // 32 j-iterations per split (64 keys each)

typedef __attribute__((ext_vector_type(8)))  short bf16x8;   // 8 bf16 = 4 VGPRs (MFMA A/B frag)
typedef __attribute__((ext_vector_type(4)))  short bf16x4;
typedef __attribute__((ext_vector_type(4)))  float f32x4;    // 16x16 MFMA C/D frag
typedef __attribute__((ext_vector_type(16))) float f32x16;   // 32x32 MFMA C/D frag

// fp32 -> bf16 round-to-nearest-even, bit pattern as short
__device__ __forceinline__ short f2bf(float f) {
    unsigned u = __float_as_uint(f);
    return (short)((u + 0x7FFFu + ((u >> 16) & 1u)) >> 16);
}

// LDS-only barrier: vm loads (K/V register prefetches) stay in flight.
// sched_barrier fences per rule #18 (no hoisting across the asm wait).
#define BAR_LGKM() do {                                                       \
    asm volatile("s_waitcnt lgkmcnt(0)" ::: "memory");                        \
    __builtin_amdgcn_sched_barrier(0);                                        \
    __builtin_amdgcn_s_barrier();                                             \
    __builtin_amdgcn_sched_barrier(0);                                        \
} while (0)

// ---------------------------------------------------------------------------
// Fused projection GEMMs, one launch. grid = (64, 8, 2).  (unchanged from R8)
// Epilogues write K/V PRE-PACKED in fragment-lane order (16B units;
// lane = hi*32 + l31):
//  K: tile ((J*4+c)*8+tp)*2+kh holds K[J*64+kh*32+l31][c*128+tp*16+hi*8+..7]
//  V: tile (J*8+wv*4+n2)*4+g   holds V^T[wv*128+n2*32+l31][J*64+g*16+hi*8+..7]
// ---------------------------------------------------------------------------
__global__ __launch_bounds__(256, 2) void proj_gemms(
    const float* __restrict__ Y, const float* __restrict__ Z,
    const float* __restrict__ Wk, const float* __restrict__ Wv,
    unsigned short* __restrict__ keyb, unsigned short* __restrict__ vtb)
{
    __shared__ short sA[64*128];   // 16 KB
    __shared__ short sB[64*128];   // 16 KB
    const float *A, *Bm;
    unsigned short* C;
    int m0, n0;
    const bool kpath = (blockIdx.z == 0);
    if (kpath) {
        A = Y; Bm = Wk; C = keyb;
        m0 = blockIdx.x * 64; n0 = blockIdx.y * 64;
    } else {
        int lin = blockIdx.x * 8 + blockIdx.y;
        if (lin >= 256) return;                 // value GEMM needs 256 tiles
        A = Wv; Bm = Z; C = vtb;
        m0 = (lin >> 6) * 64; n0 = (lin & 63) * 64;
    }
    const int tid  = threadIdx.x;
    const int wave = tid >> 6;
    const int lane = tid & 63;
    const int quad = lane >> 4;
    const int l15  = lane & 15;

    f32x4 acc[4];
    #pragma unroll
    for (int n = 0; n < 4; ++n) { acc[n][0]=0.f; acc[n][1]=0.f; acc[n][2]=0.f; acc[n][3]=0.f; }

    float4 ra[8], rb[8];
    #pragma unroll
    for (int it = 0; it < 8; ++it) {            // prefetch kc=0
        int f = it*1024 + tid*4, row = f >> 7, col = f & 127;
        ra[it] = *(const float4*)(A  + (size_t)(m0+row)*DDIM + col);
        rb[it] = *(const float4*)(Bm + (size_t)(n0+row)*DDIM + col);
    }

    for (int kc = 0; kc < DDIM; kc += 128) {
        __syncthreads();                        // LDS free (prev MFMA done)
        #pragma unroll
        for (int it = 0; it < 8; ++it) {
            int f = it*1024 + tid*4;
            bf16x4 a4; a4[0]=f2bf(ra[it].x); a4[1]=f2bf(ra[it].y); a4[2]=f2bf(ra[it].z); a4[3]=f2bf(ra[it].w);
            *(bf16x4*)(sA + f) = a4;
            bf16x4 b4; b4[0]=f2bf(rb[it].x); b4[1]=f2bf(rb[it].y); b4[2]=f2bf(rb[it].z); b4[3]=f2bf(rb[it].w);
            *(bf16x4*)(sB + f) = b4;
        }
        __syncthreads();                        // staged visible
        if (kc + 128 < DDIM) {                  // prefetch kc+1 (in flight under MFMA)
            #pragma unroll
            for (int it = 0; it < 8; ++it) {
                int f = it*1024 + tid*4, row = f >> 7, col = f & 127;
                ra[it] = *(const float4*)(A  + (size_t)(m0+row)*DDIM + kc + 128 + col);
                rb[it] = *(const float4*)(Bm + (size_t)(n0+row)*DDIM + kc + 128 + col);
            }
        }
        #pragma unroll
        for (int t = 0; t < 4; ++t) {
            bf16x8 af = *(const bf16x8*)(sA + (wave*16 + l15)*128 + t*32 + quad*8);
            #pragma unroll
            for (int n = 0; n < 4; ++n) {
                bf16x8 bfr = *(const bf16x8*)(sB + (n*16 + l15)*128 + t*32 + quad*8);
                acc[n] = __builtin_amdgcn_mfma_f32_16x16x32_bf16(af, bfr, acc[n], 0, 0, 0);
            }
        }
    }
    // packed epilogue
    #pragma unroll
    for (int n = 0; n < 4; ++n)
        #pragma unroll
        for (int r = 0; r < 4; ++r) {
            int m  = m0 + wave*16 + quad*4 + r;
            int nn = n0 + n*16 + l15;
            unsigned short v = (unsigned short)f2bf(acc[n][r]);
            size_t off;
            if (kpath) {        // s=m (key row), d=nn
                int J = m >> 6, kh = (m >> 5) & 1, ls = m & 31;
                int c = nn >> 7, tp = (nn >> 4) & 7, hd = (nn >> 3) & 1, d7 = nn & 7;
                off = (size_t)(((J*4 + c)*8 + tp)*2 + kh)*512 + (hd*32 + ls)*8 + d7;
            } else {            // dv=m, key=nn
                int J = nn >> 6, g = (nn >> 4) & 3, hk = (nn >> 3) & 1, k7 = nn & 7;
                int wv = m >> 7, n2 = (m >> 5) & 3, lv = m & 31;
                off = (size_t)((J*8 + wv*4 + n2)*4 + g)*512 + (hk*32 + lv)*8 + k7;
            }
            C[off] = v;
        }
}

// ---------------------------------------------------------------------------
// Fused attention, R12 = R8 geometry + R10's T15 j-pipeline, sized to fit.
// R10/R11 post-mortem: pipeline state at 64-rows/wave blew the 256-reg arch
// cap (VGPR pinned 256, FETCH/WRITE scratch inflation). At R8's 32-rows/wave
// the same skeleton fits: kf48 + vf64 + SC16 + SN16 + pf8 + temps ~15 = ~167
// arch + o64 acc = ~231 <= 256 -> 2 waves/SIMD kept (launch_bounds(128,2)).
// Pipeline per j (skeleton race-proven in R10: every sSt/sPex write->read
// crosses exactly one barrier):
//   A: tmax(j) store          | B: QK(j+1) ph0-3   (fills BAR1 wait)
//   BAR1                      | C: exp2/pf(j) build+store
//   D1: QK(j+1) ph4-5         | BAR2
//   E: l/m update, rescale    | F: PV(j), pure 16 MFMAs (V all-resident)
//   D2: QK(j+1) ph6-7 + V(j+1) all 4 windows + next kf(0,1)
// K/V from R8's PACKED layouts (coalesced 1KB wave-loads to regs); Q in LDS;
// T13 defer-max log2 softmax; XCD-split swizzle keeps K/V L2-resident.
// grid = 1024 (4 blocks/CU), block = 128 (one wk pair).
// ---------------------------------------------------------------------------
__global__ __launch_bounds__(128, 2) void attn_fused(
    const float* __restrict__ X,            // [16384][512] fp32
    const unsigned short* __restrict__ Kb,  // key bf16, PACKED (4 MB)
    const unsigned short* __restrict__ Vt,  // V^T bf16, PACKED (2 MB)
    float* __restrict__ Opart,              // [NS][16384][256]
    float* __restrict__ Mpart,              // [NS][16384] (log2 domain)
    float* __restrict__ Lpart)              // [NS][16384]
{
    // 0     : sQ 32KB [t2=32][lane]x16B
    // 32768 : sPex 4KB [wk*2+ks][lane]x16B P A-frags
    // 36864 : sSt 512B [wk*2+slot][32] floats
    __shared__ __align__(16) char smem[37376];
    char* sQ   = smem;
    char* sPex = smem + 32768;
    float* sSt = (float*)(smem + 36864);

    const int tid  = threadIdx.x;
    const int wk   = tid >> 6;      // 0..1: key-half for QK / dv-half for PV
    const int lane = tid & 63;
    const int l31  = lane & 31;
    const int hi   = lane >> 5;

    // XCD-split swizzle: bid&7 = XCD; XCD 0-3 -> split 0, 4-7 -> split 1.
    const int bid   = blockIdx.x;          // 0..1023
    const int xcd   = bid & 7;
    const int slot  = bid >> 3;            // 0..127
    const int split = xcd >> 2;
    const int q0    = ((xcd & 3)*128 + slot) * 32;
    // 1/sqrt(512) * log2(e): softmax runs in log2 domain (exp2)
    const float scale = 0.04419417382415922f * 1.4426950408889634f;

    // ---- prologue: stage this block's 32 Q frag-tiles to LDS (wk splits) ----
    {
        const float* xrow = X + (size_t)(q0 + l31)*DDIM + hi*8;
        #pragma unroll
        for (int i = 0; i < 16; ++i) {
            const int t2 = wk*16 + i;
            float4 a = *(const float4*)(xrow + t2*16);
            float4 b = *(const float4*)(xrow + t2*16 + 4);
            bf16x8 q;
            q[0]=f2bf(a.x*scale); q[1]=f2bf(a.y*scale); q[2]=f2bf(a.z*scale); q[3]=f2bf(a.w*scale);
            q[4]=f2bf(b.x*scale); q[5]=f2bf(b.y*scale); q[6]=f2bf(b.z*scale); q[7]=f2bf(b.w*scale);
            *(bf16x8*)(sQ + t2*1024 + lane*16) = q;
        }
    }

    // O acc: D[row=q][col=dv], wave's dv-half = wk*128 + n*32 + l31.
    f32x16 o[4];
    #pragma unroll
    for (int n = 0; n < 4; ++n)
        #pragma unroll
        for (int r = 0; r < 16; ++r) o[n][r] = 0.f;
    float m_r = -1e30f, l_r = 0.f;       // shared across wk pair

    // packed base pointers (this wave's key-half / dv-half, lane folded in)
    const int Jg0 = split * NJ;
    const char* kp = (const char*)Kb + (size_t)Jg0*65536 + wk*1024 + lane*16;
    const char* vp = (const char*)Vt + (size_t)Jg0*32768 + wk*16384 + lane*16;
    // K frag (h,t): kp + (h>>1)*16384 + (((h&1)*4+t)*2)*1024
    // V frag (n,g): vp + n*4096 + g*1024
    #define KOFF(h_, t_) ((size_t)((h_)>>1)*16384 + (size_t)((((h_)&1)*4 + (t_))*2)*1024)

    bf16x8 kf[3][4];                    // depth-2 ring (48 VGPR)
    bf16x8 vf[4][4];                    // all 4 V windows resident (64 VGPR)
    f32x16 sA_, sB_;                    // s double buffer (static names)

    BAR_LGKM();                         // Q visible to the pair

    #define LD_KF(buf_, h_)                                                   \
        do { _Pragma("unroll")                                                \
             for (int t_ = 0; t_ < 4; ++t_)                                   \
                 kf[buf_][t_] = *(const bf16x8*)(kp + KOFF(h_, t_));          \
        } while (0)

    // load ALL FOUR V windows of the tile at vp + voff_
    #define LD_V4(voff_)                                                      \
        do { _Pragma("unroll")                                                \
             for (int g_ = 0; g_ < 4; ++g_)                                   \
                 _Pragma("unroll")                                            \
                 for (int n_ = 0; n_ < 4; ++n_)                               \
                     vf[g_][n_] = *(const bf16x8*)(vp + (voff_)               \
                         + n_*4096 + g_*1024);                                \
        } while (0)

    const char* qb = sQ + lane*16;

    // one QK phase: 4 MFMAs consuming kf[buf_], Q k-steps h_*4..h_*4+3
    #define QK_PH(S_, buf_, h_)                                               \
        do {                                                                  \
            __builtin_amdgcn_s_setprio(1);                                    \
            _Pragma("unroll")                                                 \
            for (int t_ = 0; t_ < 4; ++t_) {                                  \
                bf16x8 qv_ = *(const bf16x8*)(qb + ((h_)*4 + t_)*1024);       \
                S_ = __builtin_amdgcn_mfma_f32_32x32x16_bf16(                 \
                        kf[buf_][t_], qv_, S_, 0, 0, 0);                      \
            }                                                                 \
            __builtin_amdgcn_s_setprio(0);                                    \
        } while (0)

    // ---- prologue: QK(0) -> sA_, V(0) all windows, kf ready for QK(1) ----
    LD_KF(0, 0); LD_KF(1, 1);
    #pragma unroll
    for (int r = 0; r < 16; ++r) sA_[r] = 0.f;
    LD_KF(2, 2); QK_PH(sA_, 0, 0);
    LD_KF(0, 3); QK_PH(sA_, 1, 1);
    LD_KF(1, 4); QK_PH(sA_, 2, 2);
    LD_KF(2, 5); QK_PH(sA_, 0, 3);
    LD_KF(0, 6); QK_PH(sA_, 1, 4);
    LD_KF(1, 7); QK_PH(sA_, 2, 5);
    LD_V4(0);    QK_PH(sA_, 0, 6);
    QK_PH(sA_, 1, 7);
    kp += 65536;
    LD_KF(0, 0); LD_KF(1, 1);           // tile-1 h0,h1 for ITER(0)'s B

    // ---------------- pipelined iteration ----------------
    #define ITER(jv, SC, SN)                                                  \
    {                                                                         \
        const bool hasN = (jv) + 1 < NJ;                                      \
        /* A: tile max of SC, store slot0 */                                  \
        float tmx;                                                            \
        {                                                                     \
            float v = fmaxf(fmaxf(fmaxf(SC[0],SC[1]),fmaxf(SC[2],SC[3])),     \
                            fmaxf(fmaxf(SC[4],SC[5]),fmaxf(SC[6],SC[7])));    \
            v = fmaxf(v, fmaxf(fmaxf(fmaxf(SC[8],SC[9]),fmaxf(SC[10],SC[11])), \
                               fmaxf(fmaxf(SC[12],SC[13]),fmaxf(SC[14],SC[15])))); \
            v = fmaxf(v, __shfl_xor(v, 32));                                  \
            tmx = v;                                                          \
            if (lane < 32) sSt[(wk*2 + 0)*32 + lane] = v;                     \
        }                                                                     \
        /* B: QK(jv+1) phases 0-3 into SN (hides BAR1 wait) */                \
        if (hasN) {                                                           \
            _Pragma("unroll")                                                 \
            for (int r = 0; r < 16; ++r) SN[r] = 0.f;                         \
            LD_KF(2, 2); QK_PH(SN, 0, 0);                                     \
            LD_KF(0, 3); QK_PH(SN, 1, 1);                                     \
            LD_KF(1, 4); QK_PH(SN, 2, 2);                                     \
            LD_KF(2, 5); QK_PH(SN, 0, 3);                                     \
        }                                                                     \
        BAR_LGKM();                                         /* exchange 1 */  \
        /* C: mn/upd/exp2/tsum + pf build + stores */                         \
        bool upd; float mn, tsum, alpha;                                      \
        bf16x8 pf[2];                                                         \
        {                                                                     \
            float to = sSt[((wk^1)*2 + 0)*32 + l31];                          \
            float tj = fmaxf(tmx, to);                                        \
            upd = tj > m_r + 8.0f;              /* T13 defer-max */           \
            mn  = upd ? tj : m_r;                                             \
            alpha = upd ? exp2f(m_r - mn) : 1.0f;                             \
            float ts = 0.f;                                                   \
            _Pragma("unroll")                                                 \
            for (int r = 0; r < 16; ++r) {                                    \
                float pv = exp2f(SC[r] - mn); SC[r] = pv; ts += pv;           \
            }                                                                 \
            ts += __shfl_xor(ts, 32);                                         \
            tsum = ts;                                                        \
            if (lane < 32) sSt[(wk*2 + 1)*32 + lane] = ts;                    \
            _Pragma("unroll")                                                 \
            for (int ks = 0; ks < 2; ++ks) {                                  \
                int wA, wB, wC, wD;                                           \
                asm("v_cvt_pk_bf16_f32 %0, %1, %2" : "=v"(wA) : "v"(SC[8*ks+0]), "v"(SC[8*ks+1])); \
                asm("v_cvt_pk_bf16_f32 %0, %1, %2" : "=v"(wB) : "v"(SC[8*ks+2]), "v"(SC[8*ks+3])); \
                asm("v_cvt_pk_bf16_f32 %0, %1, %2" : "=v"(wC) : "v"(SC[8*ks+4]), "v"(SC[8*ks+5])); \
                asm("v_cvt_pk_bf16_f32 %0, %1, %2" : "=v"(wD) : "v"(SC[8*ks+6]), "v"(SC[8*ks+7])); \
                asm("v_permlane32_swap_b32 %0, %1" : "+v"(wA), "+v"(wC));     \
                asm("v_permlane32_swap_b32 %0, %1" : "+v"(wB), "+v"(wD));     \
                union { int w[4]; bf16x8 v; } u;                              \
                u.w[0] = wA; u.w[1] = wB; u.w[2] = wC; u.w[3] = wD;           \
                pf[ks] = u.v;                                                 \
                *(bf16x8*)(sPex + (wk*2 + ks)*1024 + lane*16) = u.v;          \
            }                                                                 \
        }                                                                     \
        /* D1: QK(jv+1) phases 4-5 (hides BAR2 wait) */                       \
        if (hasN) {                                                           \
            LD_KF(0, 6); QK_PH(SN, 1, 4);                                     \
            LD_KF(1, 7); QK_PH(SN, 2, 5);                                     \
        }                                                                     \
        BAR_LGKM();                                         /* exchange 2 */  \
        /* E: l/m update + O rescale */                                       \
        {                                                                     \
            float tso = sSt[((wk^1)*2 + 1)*32 + l31];                         \
            l_r = l_r*alpha + (tsum + tso);                                   \
            m_r = mn;                                                         \
            if (__any(upd)) {                                                 \
                _Pragma("unroll")                                             \
                for (int r = 0; r < 16; ++r) {                                \
                    int row = (r&3) + 8*(r>>2) + 4*hi;                        \
                    float ar = __shfl(alpha, row);                            \
                    _Pragma("unroll")                                         \
                    for (int n = 0; n < 4; ++n) o[n][r] *= ar;                \
                }                                                             \
            }                                                                 \
        }                                                                     \
        /* F: PV(jv), pure 16 MFMAs (V(jv) fully resident in vf) */           \
        {                                                                     \
            const char* pb_ = sPex + lane*16;                                 \
            __builtin_amdgcn_s_setprio(1);                                    \
            _Pragma("unroll")                                                 \
            for (int g = 0; g < 4; ++g) {                                     \
                bf16x8 pa = ((g >> 1) == wk) ? pf[g & 1]                      \
                            : *(const bf16x8*)(pb_ + g*1024);                 \
                _Pragma("unroll")                                             \
                for (int n = 0; n < 4; ++n)                                   \
                    o[n] = __builtin_amdgcn_mfma_f32_32x32x16_bf16(           \
                            pa, vf[g][n], o[n], 0, 0, 0);                     \
            }                                                                 \
            __builtin_amdgcn_s_setprio(0);                                    \
        }                                                                     \
        /* D2: QK(jv+1) ph6-7; V(jv+1) all windows; next-tile kf h0,h1 */     \
        if (hasN) {                                                           \
            QK_PH(SN, 0, 6);                                                  \
            QK_PH(SN, 1, 7);                                                  \
            LD_V4(32768);                                                     \
            kp += 65536;                                                      \
            if ((jv) + 2 < NJ) { LD_KF(0, 0); LD_KF(1, 1); }                  \
        }                                                                     \
        vp += 32768;                                                          \
    }

    for (int j = 0; j < NJ; j += 2) {
        ITER(j,     sA_, sB_);
        ITER(j + 1, sB_, sA_);
    }
    #undef ITER
    #undef QK_PH
    #undef LD_V4
    #undef LD_KF
    #undef KOFF

    // ---- epilogue: shared (m,l) across wk; disjoint dv halves -> no merge ----
    const size_t base = (size_t)split * NROWS;
    if (wk == 0 && lane < 32) {
        Mpart[base + q0 + lane] = m_r;      // log2 domain
        Lpart[base + q0 + lane] = l_r;
    }
    #pragma unroll
    for (int r = 0; r < 16; ++r) {
        int row = (r&3) + 8*(r>>2) + 4*hi;
        float* orow = Opart + (base + q0 + row) * (size_t)DVDIM + wk*128;
        #pragma unroll
        for (int n = 0; n < 4; ++n)
            orow[n*32 + l31] = o[n][r];
    }
}

// ---------------------------------------------------------------------------
// Combine NS split partials: out = sum_s(Os*ws) / sum_s(ls*ws), ws=2^(ms-M)
// (Mpart is log2-domain). grid = NROWS/4, block = 256. Coalesced.
// ---------------------------------------------------------------------------
__global__ void combine_splits(
    const float* __restrict__ Opart, const float* __restrict__ Mpart,
    const float* __restrict__ Lpart, float* __restrict__ out)
{
    const int row = blockIdx.x * 4 + (threadIdx.x >> 6);
    const int dv4 = (threadIdx.x & 63) * 4;
    float M = -1e30f;
    #pragma unroll
    for (int s = 0; s < NS; ++s) M = fmaxf(M, Mpart[(size_t)s*NROWS + row]);
    float denom = 0.f;
    float4 acc = make_float4(0.f, 0.f, 0.f, 0.f);
    #pragma unroll
    for (int s = 0; s < NS; ++s) {
        float w = exp2f(Mpart[(size_t)s*NROWS + row] - M);
        denom += Lpart[(size_t)s*NROWS + row] * w;
        float4 ov = *(const float4*)(Opart + ((size_t)s*NROWS + row)*DVDIM + dv4);
        acc.x += ov.x*w; acc.y += ov.y*w; acc.z += ov.z*w; acc.w += ov.w*w;
    }
    float inv = 1.0f / denom;
    *(float4*)(out + (size_t)row*DVDIM + dv4)
        = make_float4(acc.x*inv, acc.y*inv, acc.z*inv, acc.w*inv);
}

extern "C" void kernel_launch(void* const* d_in, const int* in_sizes, int n_in,
                              void* d_out, int out_size, void* d_ws, size_t ws_size,
                              hipStream_t stream) {
    const float* X  = (const float*)d_in[0];   // [8,2048,512]
    const float* Y  = (const float*)d_in[1];   // [4096,512]
    const float* Z  = (const float*)d_in[2];   // [4096,512]
    const float* Wk = (const float*)d_in[3];   // [512,512]
    const float* Wv = (const float*)d_in[4];   // [256,512]
    float* out = (float*)d_out;

    // workspace layout (~38.3 MB)
    char* ws = (char*)d_ws;
    unsigned short* keyb = (unsigned short*)ws;                    // 4 MB, PACKED
    unsigned short* vtb  = (unsigned short*)(ws + (4u<<20));       // 2 MB, PACKED
    float* Opart = (float*)(ws + (6u<<20));                        // NS x 16 MB
    float* Mpart = (float*)(ws + (6u<<20) + (size_t)NS*NROWS*DVDIM*4);
    float* Lpart = Mpart + (size_t)NS*NROWS;

    // both projections, one launch (epilogues emit packed layouts)
    proj_gemms<<<dim3(64, 8, 2), dim3(256), 0, stream>>>(Y, Z, Wk, Wv, keyb, vtb);
    // fused attention: 1024 blocks (4/CU), j-pipelined, packed K/V to regs
    attn_fused<<<dim3(1024), dim3(128), 0, stream>>>(
        X, keyb, vtb, Opart, Mpart, Lpart);
    // merge splits
    combine_splits<<<dim3(NROWS/4), dim3(256), 0, stream>>>(Opart, Mpart, Lpart, out);
}